// Round 6
// baseline (323.923 us; speedup 1.0000x reference)
//
#include <hip/hip_runtime.h>

// Unfold: x[B=32, C=64, H=64, W=64] fp32, KH=KW=3, stride=1
// out[b][c*9 + i*3 + j][ho*62 + wo] = x[b][c][ho+i][wo+j]; out [32, 576, 3844].
//
// R6: NO LDS. One block per (b,c) channel; the 16 KB channel fits entirely
// in L1 (32 KB/CU), and k-major emission re-reads it sequentially 9x, so
// direct global loads hit L1 for 8/9 of accesses. Removes the staging
// burst + __syncthreads serialization common to R2/R3/R5 (all pinned at
// ~315 us). Each wave still writes one linear nontemporal float4 stream
// (3844 = 4*961, so a float4 never straddles a k-row).

#define B 32
#define C 64
#define H 64
#define W 64
#define HO 62
#define WO 62
#define L (HO * WO)        // 3844
#define L4 (L / 4)         // 961
#define KK 9
#define F_TOT (KK * L4)    // 8649 float4 per (b,c)

typedef float f32x4 __attribute__((ext_vector_type(4)));

__global__ __launch_bounds__(256, 8) void unfold_kernel(
    const float* __restrict__ x, float* __restrict__ out) {
    const int c   = blockIdx.x;   // 0..63
    const int b   = blockIdx.y;   // 0..31
    const int tid = threadIdx.x;  // 0..255

    const float* __restrict__ xc = x + (((size_t)(b * C + c)) << 12);  // 16 KB channel
    f32x4* __restrict__ dst4 = (f32x4*)out + (size_t)(b * C + c) * F_TOT;

    for (int f = tid; f < F_TOT; f += 256) {
        const int k  = f / L4;          // 0..8   (magic-mul div)
        const int r  = f - k * L4;      // 0..960
        const int i  = k / 3;           // 0..2
        const int j  = k - i * 3;       // 0..2
        const int l0 = r * 4;
        int ho = l0 / WO;               // magic-mul div
        int wo = l0 - ho * WO;
        int addr = (ho + i) * W + wo + j;

        float v[4];
#pragma unroll
        for (int q = 0; q < 4; ++q) {
            v[q] = xc[addr];            // L1-resident after first k-pass
            ++addr;
            ++wo;
            if (wo == WO) { wo = 0; addr += (W - WO); }
        }
        f32x4 o;
        o.x = v[0]; o.y = v[1]; o.z = v[2]; o.w = v[3];
        __builtin_nontemporal_store(o, &dst4[f]);  // global_store_dwordx4 nt
    }
}

extern "C" void kernel_launch(void* const* d_in, const int* in_sizes, int n_in,
                              void* d_out, int out_size, void* d_ws, size_t ws_size,
                              hipStream_t stream) {
    const float* x = (const float*)d_in[0];
    float* out = (float*)d_out;

    dim3 block(256, 1, 1);
    dim3 grid(C, B, 1);  // 2048 blocks; no LDS -> 8 blocks/CU (thread-limited)
    unfold_kernel<<<grid, block, 0, stream>>>(x, out);
}